// Round 2
// 412.269 us; speedup vs baseline: 1.0054x; 1.0054x over previous
//
#include <hip/hip_runtime.h>
#include <math.h>

#define H  14
#define C  7
#define HC 98
#define FIN 256
#define NEG_SLOPE 0.2f
#define NPB 32
#define AGG_BLOCK (NPB * H)   // 448 = 7 full waves
#define LOG2E 1.44269504088896f

#define BSHIFT 9
#define BSIZE  512
#define NBUCK_MAX 256

typedef __attribute__((ext_vector_type(8))) short short8;
typedef __attribute__((ext_vector_type(4))) float floatx4;
typedef _Float16 h2 __attribute__((ext_vector_type(2)));

#define WT_ROWS   112            // 98 cols zero-padded to 7*16
#define WT_STRIDE 264            // 256 + 8 pad (bf16 units)
#define XA_STRIDE 40             // 32 + 8 pad (bf16 units)
#define VS_STRIDE 99             // 98 + 1 pad (f32 units)

// f32 -> bf16 bits, round-to-nearest-even (MFMA staging only)
__device__ __forceinline__ unsigned bf16r(float f) {
    unsigned u = __float_as_uint(f);
    return (u + 0x7FFFu + ((u >> 16) & 1u)) >> 16;
}

// ---- fp16 helpers via native _Float16 vectors (no hip_fp16.h dependence) ----
__device__ __forceinline__ h2 u2h(unsigned u) { return __builtin_bit_cast(h2, u); }
__device__ __forceinline__ unsigned hpk(float a, float b) {
    h2 v = { (_Float16)a, (_Float16)b };
    return __builtin_bit_cast(unsigned, v);
}
__device__ __forceinline__ float hhi(unsigned w) {
    unsigned short s = (unsigned short)(w >> 16);
    return (float)__builtin_bit_cast(_Float16, s);
}

// ---------------- bucketed CSR construction (no self loops) ----------------

__global__ void k_zero(int* __restrict__ p, int n) {
    int i = blockIdx.x * blockDim.x + threadIdx.x;
    if (i < n) p[i] = 0;
}

__global__ __launch_bounds__(256) void k_hist(const int* __restrict__ ei, int E,
                                              int* __restrict__ gcnt, int nb) {
    __shared__ int hist[NBUCK_MAX];
    const int t = threadIdx.x;
    for (int i = t; i < nb; i += 256) hist[i] = 0;
    __syncthreads();
    const int stride = gridDim.x * 256;
    for (int e = blockIdx.x * 256 + t; e < E; e += stride)
        atomicAdd(&hist[ei[E + e] >> BSHIFT], 1);
    __syncthreads();
    for (int i = t; i < nb; i += 256)
        if (hist[i]) atomicAdd(gcnt + i, hist[i]);
}

__global__ __launch_bounds__(1024) void k_bscan(const int* __restrict__ gcnt,
                                                int* __restrict__ boff, int* __restrict__ bcur,
                                                int* __restrict__ row_ptr, int nb, int N) {
    __shared__ int sd[1024];
    int t = threadIdx.x;
    int own = (t < nb) ? gcnt[t] : 0;
    sd[t] = own;
    __syncthreads();
    #pragma unroll
    for (int off = 1; off < 1024; off <<= 1) {
        int v = (t >= off) ? sd[t - off] : 0;
        __syncthreads();
        sd[t] += v;
        __syncthreads();
    }
    if (t < nb) {
        boff[t + 1] = sd[t];
        bcur[t] = sd[t] - own;          // exclusive
        if (t == nb - 1) row_ptr[N] = sd[t];
    }
    if (t == 0) boff[0] = 0;
}

__global__ __launch_bounds__(256) void k_part(const int* __restrict__ ei, int E,
                                              int* __restrict__ bcur, int2* __restrict__ pedge,
                                              int nb) {
    __shared__ int hist[NBUCK_MAX];
    __shared__ int start[NBUCK_MAX];
    const int t = threadIdx.x;
    const int chunk = (E + gridDim.x - 1) / gridDim.x;
    const int c0 = blockIdx.x * chunk;
    const int c1 = min(c0 + chunk, E);
    for (int i = t; i < nb; i += 256) hist[i] = 0;
    __syncthreads();
    for (int e = c0 + t; e < c1; e += 256)
        atomicAdd(&hist[ei[E + e] >> BSHIFT], 1);
    __syncthreads();
    for (int i = t; i < nb; i += 256) {
        int h = hist[i];
        start[i] = h ? atomicAdd(bcur + i, h) : 0;
        hist[i] = 0;                     // reuse as local cursor
    }
    __syncthreads();
    for (int e = c0 + t; e < c1; e += 256) {
        int s = ei[e], d = ei[E + e];
        int b = d >> BSHIFT;
        int pos = start[b] + atomicAdd(&hist[b], 1);
        pedge[pos] = make_int2(s, d);
    }
}

__global__ __launch_bounds__(512) void k_bcsr(const int2* __restrict__ pedge,
                                              const int* __restrict__ boff,
                                              int* __restrict__ row_ptr, int* __restrict__ col,
                                              int N) {
    __shared__ int cnt[BSIZE];
    __shared__ int sc[BSIZE];
    __shared__ int cur[BSIZE];
    const int b  = blockIdx.x;
    const int t  = threadIdx.x;
    const int e0 = boff[b], e1 = boff[b + 1];
    const int base = b << BSHIFT;
    const int nv = min(BSIZE, N - base);
    cnt[t] = 0;
    __syncthreads();
    for (int e = e0 + t; e < e1; e += 512)
        atomicAdd(&cnt[pedge[e].y - base], 1);
    __syncthreads();
    sc[t] = cnt[t];
    __syncthreads();
    #pragma unroll
    for (int off = 1; off < BSIZE; off <<= 1) {
        int v = (t >= off) ? sc[t - off] : 0;
        __syncthreads();
        sc[t] += v;
        __syncthreads();
    }
    if (t < nv) {
        int excl = sc[t] - cnt[t];
        row_ptr[base + t] = e0 + excl;
        cur[t] = excl;
    }
    __syncthreads();
    for (int e = e0 + t; e < e1; e += 512) {
        int2 r = pedge[e];
        int d = r.y - base;
        int pos = e0 + atomicAdd(&cur[d], 1);
        col[pos] = r.x;
    }
}

// ---------------- layer-1: MFMA projection fused with pack ----------------

__global__ void k_convW(const float* __restrict__ W, unsigned short* __restrict__ WtG) {
    int id = blockIdx.x * blockDim.x + threadIdx.x;   // 112*256
    int n = id >> 8, k = id & 255;
    float v = (n < HC) ? W[k * HC + n] : 0.f;
    WtG[id] = (unsigned short)(__float_as_uint(v) >> 16);  // exact: inputs bf16-rounded
}

// xpack[n*H+h] = {7 msg fp16, src-logit*log2e fp16}; aldst[n*H+h] = dst logit*log2e f32
__global__ __launch_bounds__(256) void k_proj1_mfma(
    const float* __restrict__ x, const unsigned short* __restrict__ WtG,
    const float* __restrict__ asrc, const float* __restrict__ adst,
    uint4* __restrict__ xpack, float* __restrict__ aldst, int N)
{
    __shared__ unsigned short wt_s[WT_ROWS * WT_STRIDE];  // 59136 B (reused as f32 vals)
    __shared__ unsigned short xa_s[64 * XA_STRIDE];       //  5120 B
    __shared__ float as_s[HC], ad_s[HC];
    float* vals_s = (float*)wt_s;                          // 64*99*4 = 25344 B < 59136
    const int t  = threadIdx.x;
    const int wv = t >> 6;
    const int l  = t & 63;
    const int ln = l & 15;
    const int qd = l >> 4;
    const int rowBase = blockIdx.x * 64;

    #pragma unroll
    for (int i = 0; i < 14; ++i) {
        int f = i * 256 + t;            // uint4 index, 3584 total (32 per row)
        int r = f >> 5, pos = f & 31;
        *(uint4*)(wt_s + r * WT_STRIDE + pos * 8) = ((const uint4*)WtG)[f];
    }
    if (t < HC) { as_s[t] = asrc[t]; ad_s[t] = adst[t]; }

    floatx4 acc[7] = {};

    for (int step = 0; step < 8; ++step) {
        const int k0 = step * 32;
        __syncthreads();
        #pragma unroll
        for (int i = 0; i < 2; ++i) {
            int idx = i * 256 + t;       // 512 float4 total
            int r = idx >> 3, c4 = idx & 7;
            int gr = rowBase + r; if (gr >= N) gr = N - 1;
            float4 v = *(const float4*)(x + (size_t)gr * FIN + k0 + c4 * 4);
            ushort4 u;
            u.x = (unsigned short)(__float_as_uint(v.x) >> 16);
            u.y = (unsigned short)(__float_as_uint(v.y) >> 16);
            u.z = (unsigned short)(__float_as_uint(v.z) >> 16);
            u.w = (unsigned short)(__float_as_uint(v.w) >> 16);
            *(ushort4*)(xa_s + r * XA_STRIDE + c4 * 4) = u;
        }
        __syncthreads();
        short8 a = *(const short8*)(xa_s + ((wv << 4) + ln) * XA_STRIDE + qd * 8);
        #pragma unroll
        for (int ct = 0; ct < 7; ++ct) {
            short8 b = *(const short8*)(wt_s + (ct * 16 + ln) * WT_STRIDE + k0 + qd * 8);
            acc[ct] = __builtin_amdgcn_mfma_f32_16x16x32_bf16(a, b, acc[ct], 0, 0, 0);
        }
    }

    __syncthreads();                    // wt_s dead; reuse as vals_s
    // C/D: col = ln, row = qd*4 + r (local row = wv*16 + qd*4 + r)
    #pragma unroll
    for (int ct = 0; ct < 7; ++ct) {
        int colg = ct * 16 + ln;
        if (colg < HC) {
            #pragma unroll
            for (int r = 0; r < 4; ++r)
                vals_s[((wv << 4) + (qd << 2) + r) * VS_STRIDE + colg] = acc[ct][r];
        }
    }
    __syncthreads();

    // pack: 64 nodes x 14 heads = 896 records
    for (int p = t; p < 64 * H; p += 256) {
        int nl = p / H, h = p - nl * H;
        int gn = rowBase + nl;
        if (gn >= N) break;
        const float* vp = vals_s + nl * VS_STRIDE + h * C;
        float v[C];
        float s1 = 0.f, s2 = 0.f;
        #pragma unroll
        for (int c2 = 0; c2 < C; ++c2) {
            float f = vp[c2];
            v[c2] = f;
            s1 = fmaf(f, as_s[h * C + c2], s1);
            s2 = fmaf(f, ad_s[h * C + c2], s2);
        }
        uint4 pk;
        pk.x = hpk(v[0], v[1]);
        pk.y = hpk(v[2], v[3]);
        pk.z = hpk(v[4], v[5]);
        pk.w = hpk(v[6], s1 * LOG2E);
        xpack[(size_t)gn * H + h] = pk;
        aldst[(size_t)gn * H + h] = s2 * LOG2E;
    }
}

// ---------------- layer-2 projection + pack (thread per node) ----------------

__global__ __launch_bounds__(256) void k_proj2_pack(
    const float* __restrict__ h1, const float* __restrict__ W,
    const float* __restrict__ asrc, const float* __restrict__ adst,
    uint4* __restrict__ xpack, float* __restrict__ aldst, int N)
{
    __shared__ float Ws[C * HC];
    __shared__ float as_s[HC], ad_s[HC];
    const int t = threadIdx.x;
    for (int i = t; i < C * HC; i += 256) Ws[i] = W[i];
    if (t < HC) { as_s[t] = asrc[t]; ad_s[t] = adst[t]; }
    __syncthreads();
    int n = blockIdx.x * 256 + t;
    if (n >= N) return;
    float xr[C];
    #pragma unroll
    for (int c2 = 0; c2 < C; ++c2) xr[c2] = h1[(size_t)n * C + c2];
    #pragma unroll
    for (int h = 0; h < H; ++h) {
        float v[C], s1 = 0.f, s2 = 0.f;
        #pragma unroll
        for (int c2 = 0; c2 < C; ++c2) {
            float acc = 0.f;
            #pragma unroll
            for (int k = 0; k < C; ++k)
                acc = fmaf(xr[k], Ws[k * HC + h * C + c2], acc);
            v[c2] = acc;
            s1 = fmaf(acc, as_s[h * C + c2], s1);
            s2 = fmaf(acc, ad_s[h * C + c2], s2);
        }
        uint4 pk;
        pk.x = hpk(v[0], v[1]);
        pk.y = hpk(v[2], v[3]);
        pk.z = hpk(v[4], v[5]);
        pk.w = hpk(v[6], s1 * LOG2E);
        xpack[(size_t)n * H + h] = pk;     // 224 B contiguous per thread
        aldst[(size_t)n * H + h] = s2 * LOG2E;
    }
}

// ---------------- fused aggregation ----------------
// thread = (node, head); implicit self loop.
// No online rescale: softmax is shift-invariant, so use FIXED per-thread shift
// K = leaky(ld + 2) (ld = dst logit, constant per thread; all in log2 domain).
// p = 2^(leaky(l) - K) is bounded (~33 max) and never catastrophically small,
// so: den = plain f32 sum; channel maxes = packed fp16 mul+max (v_pk_*_f16).
#define AGG_STEP(DEN, REC)                                              \
    {                                                                   \
        float l = hhi((REC).w) + ld;                                    \
        float p = __builtin_amdgcn_exp2f(fmaxf(l, 0.2f * l) - K);       \
        DEN += p;                                                       \
        _Float16 ph = (_Float16)p;                                      \
        h2 p2 = { ph, ph };                                             \
        m0 = __builtin_elementwise_max(m0, p2 * u2h((REC).x));          \
        m1 = __builtin_elementwise_max(m1, p2 * u2h((REC).y));          \
        m2 = __builtin_elementwise_max(m2, p2 * u2h((REC).z));          \
        m3 = __builtin_elementwise_max(m3, p2 * u2h((REC).w));          \
    }

template<int LAYER>
__global__ __launch_bounds__(AGG_BLOCK) void k_agg(
    const int* __restrict__ row_ptr, const int* __restrict__ col,
    const uint4* __restrict__ xpack, const float* __restrict__ aldst,
    const float* __restrict__ bias,
    float* __restrict__ h1, float* __restrict__ out, int N)
{
    __shared__ float vals[NPB][HC];
    __shared__ float fv[NPB][C];
    const int t  = threadIdx.x;
    const int nl = t / H;
    const int h  = t - nl * H;
    const int n  = blockIdx.x * NPB + nl;

    if (n < N) {
        const int e0  = row_ptr[n];
        const int deg = row_ptr[n + 1] - e0;
        const float ld = aldst[(size_t)n * H + h];           // already * log2e
        const float kb = ld + 2.0f * LOG2E;
        const float K  = fmaxf(kb, 0.2f * kb);               // leaky(ld + 2), log2 domain

        float denA, denB = 0.f;
        h2 m0, m1, m2, m3;
        {
            uint4 pk = xpack[(size_t)n * H + h];             // implicit self loop
            float l = hhi(pk.w) + ld;
            float p = __builtin_amdgcn_exp2f(fmaxf(l, 0.2f * l) - K);
            denA = p;
            _Float16 ph = (_Float16)p;
            h2 p2 = { ph, ph };
            m0 = p2 * u2h(pk.x);
            m1 = p2 * u2h(pk.y);
            m2 = p2 * u2h(pk.z);
            m3 = p2 * u2h(pk.w);                             // hi half = p*logit, ignored
        }

        if (deg > 0) {
            const int last = deg - 1;
            // record pipeline (indices 0..last), col queue 4 ahead
            int c0 = col[e0];
            int c1 = col[e0 + min(1, last)];
            int c2 = col[e0 + min(2, last)];
            int c3 = col[e0 + min(3, last)];
            uint4 r0 = xpack[(size_t)c0 * H + h];
            uint4 r1 = xpack[(size_t)c1 * H + h];
            uint4 r2 = xpack[(size_t)c2 * H + h];
            uint4 r3 = xpack[(size_t)c3 * H + h];
            c0 = col[e0 + min(4, last)];
            c1 = col[e0 + min(5, last)];
            c2 = col[e0 + min(6, last)];
            c3 = col[e0 + min(7, last)];
            for (int i = 0; i < deg; i += 2) {
                uint4 curA = r0, curB = r1;
                r0 = r2; r1 = r3;
                r2 = xpack[(size_t)c0 * H + h];
                r3 = xpack[(size_t)c1 * H + h];
                c0 = c2; c1 = c3;
                c2 = col[e0 + min(i + 8, last)];
                c3 = col[e0 + min(i + 9, last)];
                AGG_STEP(denA, curA);                        // edge i
                if (i + 1 < deg) AGG_STEP(denB, curB);       // edge i+1
            }
        }

        float rd = 1.f / (denA + denB);
        float* vp = &vals[nl][h * C];
        vp[0] = (float)m0.x * rd; vp[1] = (float)m0.y * rd;
        vp[2] = (float)m1.x * rd; vp[3] = (float)m1.y * rd;
        vp[4] = (float)m2.x * rd; vp[5] = (float)m2.y * rd;
        vp[6] = (float)m3.x * rd;
    }
    __syncthreads();

    if (t < NPB * C) {
        int nl2 = t / C, c2 = t - nl2 * C;
        int n2 = blockIdx.x * NPB + nl2;
        if (n2 < N) {
            float s = 0.f;
            #pragma unroll
            for (int hh = 0; hh < H; ++hh) s += vals[nl2][hh * C + c2];
            float o = s * (1.f / H) + bias[c2];
            if (LAYER == 1) h1[(size_t)n2 * C + c2] = fmaxf(o, 0.f);
            else            fv[nl2][c2] = o;
        }
    }
    if (LAYER == 2) {
        __syncthreads();
        if (t < NPB) {
            int n2 = blockIdx.x * NPB + t;
            if (n2 < N) {
                float mv = -1e30f;
                #pragma unroll
                for (int c2 = 0; c2 < C; ++c2) mv = fmaxf(mv, fv[t][c2]);
                float lse = 0.f;
                #pragma unroll
                for (int c2 = 0; c2 < C; ++c2) lse += __expf(fv[t][c2] - mv);
                lse = logf(lse);
                #pragma unroll
                for (int c2 = 0; c2 < C; ++c2)
                    out[(size_t)n2 * C + c2] = fv[t][c2] - mv - lse;
            }
        }
    }
}

// ---------------- launch ----------------

static inline size_t align16(size_t v) { return (v + 15) & ~(size_t)15; }

extern "C" void kernel_launch(void* const* d_in, const int* in_sizes, int n_in,
                              void* d_out, int out_size, void* d_ws, size_t ws_size,
                              hipStream_t stream)
{
    const float* x     = (const float*)d_in[0];
    const int*   ei    = (const int*)d_in[1];
    const float* W1    = (const float*)d_in[2];
    const float* asrc1 = (const float*)d_in[3];
    const float* adst1 = (const float*)d_in[4];
    const float* b1    = (const float*)d_in[5];
    const float* W2    = (const float*)d_in[6];
    const float* asrc2 = (const float*)d_in[7];
    const float* adst2 = (const float*)d_in[8];
    const float* b2    = (const float*)d_in[9];

    const int N  = in_sizes[0] / FIN;   // 100000
    const int E  = in_sizes[1] / 2;     // 1600000
    const int nb = (N + BSIZE - 1) >> BSHIFT;   // 196

    char* w = (char*)d_ws;
    uint4* xpack   = (uint4*)w; w += align16((size_t)N * H * 16);   // 22.4 MB
    int2*  pedge   = (int2*)w;  w += align16((size_t)E * 8);        // 12.8 MB
    float* aldst   = (float*)w; w += align16((size_t)N * H * 4);    //  5.6 MB
    float* h1      = (float*)w; w += align16((size_t)N * C * 4);    //  2.8 MB
    int*   row_ptr = (int*)w;   w += align16((size_t)(N + 1) * 4);
    int*   col     = (int*)w;   w += align16((size_t)E * 4);        //  6.4 MB
    int*   gcnt    = (int*)w;   w += align16((size_t)nb * 4);
    int*   boff    = (int*)w;   w += align16((size_t)(nb + 1) * 4);
    int*   bcur    = (int*)w;   w += align16((size_t)nb * 4);
    unsigned short* WtG = (unsigned short*)w; w += align16((size_t)WT_ROWS * FIN * 2);

    const int gAgg  = (N + NPB - 1) / NPB;
    const int gMfma = (N + 63) / 64;
    const int g256N = (N + 255) / 256;

    // ---- bucketed CSR build (no self loops; rebuilt every call) ----
    k_zero<<<1, 256, 0, stream>>>(gcnt, nb);
    k_hist<<<256, 256, 0, stream>>>(ei, E, gcnt, nb);
    k_bscan<<<1, 1024, 0, stream>>>(gcnt, boff, bcur, row_ptr, nb, N);
    k_part<<<256, 256, 0, stream>>>(ei, E, bcur, pedge, nb);
    k_bcsr<<<nb, 512, 0, stream>>>(pedge, boff, row_ptr, col, N);

    // ---- layer 1 ----
    k_convW<<<(WT_ROWS * FIN + 255) / 256, 256, 0, stream>>>(W1, WtG);
    k_proj1_mfma<<<gMfma, 256, 0, stream>>>(x, WtG, asrc1, adst1, xpack, aldst, N);
    k_agg<1><<<gAgg, AGG_BLOCK, 0, stream>>>(row_ptr, col, xpack, aldst, b1,
                                             h1, (float*)d_out, N);
    // ---- layer 2 ----
    k_proj2_pack<<<g256N, 256, 0, stream>>>(h1, W2, asrc2, adst2, xpack, aldst, N);
    k_agg<2><<<gAgg, AGG_BLOCK, 0, stream>>>(row_ptr, col, xpack, aldst, b2,
                                             h1, (float*)d_out, N);
}

// Round 3
// 409.850 us; speedup vs baseline: 1.0113x; 1.0059x over previous
//
#include <hip/hip_runtime.h>
#include <math.h>

#define H  14
#define C  7
#define HC 98
#define FIN 256
#define NEG_SLOPE 0.2f
#define LOG2E 1.44269504088896f

#define BSHIFT 9
#define BSIZE  512
#define NBUCK_MAX 256

typedef __attribute__((ext_vector_type(8))) short short8;
typedef __attribute__((ext_vector_type(4))) float floatx4;
typedef _Float16 h2 __attribute__((ext_vector_type(2)));

#define WT_ROWS   112            // 98 cols zero-padded to 7*16
#define WT_STRIDE 264            // 256 + 8 pad (bf16 units)
#define XA_STRIDE 40             // 32 + 8 pad (bf16 units)
#define VS_STRIDE 99             // 98 + 1 pad (f32 units)

// f32 -> bf16 bits, round-to-nearest-even (MFMA staging only)
__device__ __forceinline__ unsigned bf16r(float f) {
    unsigned u = __float_as_uint(f);
    return (u + 0x7FFFu + ((u >> 16) & 1u)) >> 16;
}

// ---- fp16 helpers via native _Float16 vectors (no hip_fp16.h dependence) ----
__device__ __forceinline__ h2 u2h(unsigned u) { return __builtin_bit_cast(h2, u); }
__device__ __forceinline__ unsigned hpk(float a, float b) {
    h2 v = { (_Float16)a, (_Float16)b };
    return __builtin_bit_cast(unsigned, v);
}
__device__ __forceinline__ float hhi(unsigned w) {
    unsigned short s = (unsigned short)(w >> 16);
    return (float)__builtin_bit_cast(_Float16, s);
}
// max-combine of packed fp16 pair across lanes (xor mask)
__device__ __forceinline__ h2 hshfl_max(h2 v, int mask) {
    int u = __builtin_bit_cast(int, v);
    int o = __shfl_xor(u, mask, 64);
    return __builtin_elementwise_max(v, u2h((unsigned)o));
}

// ---------------- bucketed CSR construction (no self loops) ----------------

__global__ void k_zero(int* __restrict__ p, int n) {
    int i = blockIdx.x * blockDim.x + threadIdx.x;
    if (i < n) p[i] = 0;
}

__global__ __launch_bounds__(256) void k_hist(const int* __restrict__ ei, int E,
                                              int* __restrict__ gcnt, int nb) {
    __shared__ int hist[NBUCK_MAX];
    const int t = threadIdx.x;
    for (int i = t; i < nb; i += 256) hist[i] = 0;
    __syncthreads();
    const int stride = gridDim.x * 256;
    for (int e = blockIdx.x * 256 + t; e < E; e += stride)
        atomicAdd(&hist[ei[E + e] >> BSHIFT], 1);
    __syncthreads();
    for (int i = t; i < nb; i += 256)
        if (hist[i]) atomicAdd(gcnt + i, hist[i]);
}

__global__ __launch_bounds__(1024) void k_bscan(const int* __restrict__ gcnt,
                                                int* __restrict__ boff, int* __restrict__ bcur,
                                                int* __restrict__ row_ptr, int nb, int N) {
    __shared__ int sd[1024];
    int t = threadIdx.x;
    int own = (t < nb) ? gcnt[t] : 0;
    sd[t] = own;
    __syncthreads();
    #pragma unroll
    for (int off = 1; off < 1024; off <<= 1) {
        int v = (t >= off) ? sd[t - off] : 0;
        __syncthreads();
        sd[t] += v;
        __syncthreads();
    }
    if (t < nb) {
        boff[t + 1] = sd[t];
        bcur[t] = sd[t] - own;          // exclusive
        if (t == nb - 1) row_ptr[N] = sd[t];
    }
    if (t == 0) boff[0] = 0;
}

__global__ __launch_bounds__(256) void k_part(const int* __restrict__ ei, int E,
                                              int* __restrict__ bcur, int2* __restrict__ pedge,
                                              int nb) {
    __shared__ int hist[NBUCK_MAX];
    __shared__ int start[NBUCK_MAX];
    const int t = threadIdx.x;
    const int chunk = (E + gridDim.x - 1) / gridDim.x;
    const int c0 = blockIdx.x * chunk;
    const int c1 = min(c0 + chunk, E);
    for (int i = t; i < nb; i += 256) hist[i] = 0;
    __syncthreads();
    for (int e = c0 + t; e < c1; e += 256)
        atomicAdd(&hist[ei[E + e] >> BSHIFT], 1);
    __syncthreads();
    for (int i = t; i < nb; i += 256) {
        int h = hist[i];
        start[i] = h ? atomicAdd(bcur + i, h) : 0;
        hist[i] = 0;                     // reuse as local cursor
    }
    __syncthreads();
    for (int e = c0 + t; e < c1; e += 256) {
        int s = ei[e], d = ei[E + e];
        int b = d >> BSHIFT;
        int pos = start[b] + atomicAdd(&hist[b], 1);
        pedge[pos] = make_int2(s, d);
    }
}

__global__ __launch_bounds__(512) void k_bcsr(const int2* __restrict__ pedge,
                                              const int* __restrict__ boff,
                                              int* __restrict__ row_ptr, int* __restrict__ col,
                                              int N) {
    __shared__ int cnt[BSIZE];
    __shared__ int sc[BSIZE];
    __shared__ int cur[BSIZE];
    const int b  = blockIdx.x;
    const int t  = threadIdx.x;
    const int e0 = boff[b], e1 = boff[b + 1];
    const int base = b << BSHIFT;
    const int nv = min(BSIZE, N - base);
    cnt[t] = 0;
    __syncthreads();
    for (int e = e0 + t; e < e1; e += 512)
        atomicAdd(&cnt[pedge[e].y - base], 1);
    __syncthreads();
    sc[t] = cnt[t];
    __syncthreads();
    #pragma unroll
    for (int off = 1; off < BSIZE; off <<= 1) {
        int v = (t >= off) ? sc[t - off] : 0;
        __syncthreads();
        sc[t] += v;
        __syncthreads();
    }
    if (t < nv) {
        int excl = sc[t] - cnt[t];
        row_ptr[base + t] = e0 + excl;
        cur[t] = excl;
    }
    __syncthreads();
    for (int e = e0 + t; e < e1; e += 512) {
        int2 r = pedge[e];
        int d = r.y - base;
        int pos = e0 + atomicAdd(&cur[d], 1);
        col[pos] = r.x;
    }
}

// ---------------- layer-1: MFMA projection fused with pack ----------------

__global__ void k_convW(const float* __restrict__ W, unsigned short* __restrict__ WtG) {
    int id = blockIdx.x * blockDim.x + threadIdx.x;   // 112*256
    int n = id >> 8, k = id & 255;
    float v = (n < HC) ? W[k * HC + n] : 0.f;
    WtG[id] = (unsigned short)(__float_as_uint(v) >> 16);  // exact: inputs bf16-rounded
}

// xpack[n*H+h] = {7 msg fp16, src-logit*log2e fp16}; aldst[n*H+h] = dst logit*log2e f32
__global__ __launch_bounds__(256) void k_proj1_mfma(
    const float* __restrict__ x, const unsigned short* __restrict__ WtG,
    const float* __restrict__ asrc, const float* __restrict__ adst,
    uint4* __restrict__ xpack, float* __restrict__ aldst, int N)
{
    __shared__ unsigned short wt_s[WT_ROWS * WT_STRIDE];  // 59136 B (reused as f32 vals)
    __shared__ unsigned short xa_s[64 * XA_STRIDE];       //  5120 B
    __shared__ float as_s[HC], ad_s[HC];
    float* vals_s = (float*)wt_s;                          // 64*99*4 = 25344 B < 59136
    const int t  = threadIdx.x;
    const int wv = t >> 6;
    const int l  = t & 63;
    const int ln = l & 15;
    const int qd = l >> 4;
    const int rowBase = blockIdx.x * 64;

    #pragma unroll
    for (int i = 0; i < 14; ++i) {
        int f = i * 256 + t;            // uint4 index, 3584 total (32 per row)
        int r = f >> 5, pos = f & 31;
        *(uint4*)(wt_s + r * WT_STRIDE + pos * 8) = ((const uint4*)WtG)[f];
    }
    if (t < HC) { as_s[t] = asrc[t]; ad_s[t] = adst[t]; }

    floatx4 acc[7] = {};

    for (int step = 0; step < 8; ++step) {
        const int k0 = step * 32;
        __syncthreads();
        #pragma unroll
        for (int i = 0; i < 2; ++i) {
            int idx = i * 256 + t;       // 512 float4 total
            int r = idx >> 3, c4 = idx & 7;
            int gr = rowBase + r; if (gr >= N) gr = N - 1;
            float4 v = *(const float4*)(x + (size_t)gr * FIN + k0 + c4 * 4);
            ushort4 u;
            u.x = (unsigned short)(__float_as_uint(v.x) >> 16);
            u.y = (unsigned short)(__float_as_uint(v.y) >> 16);
            u.z = (unsigned short)(__float_as_uint(v.z) >> 16);
            u.w = (unsigned short)(__float_as_uint(v.w) >> 16);
            *(ushort4*)(xa_s + r * XA_STRIDE + c4 * 4) = u;
        }
        __syncthreads();
        short8 a = *(const short8*)(xa_s + ((wv << 4) + ln) * XA_STRIDE + qd * 8);
        #pragma unroll
        for (int ct = 0; ct < 7; ++ct) {
            short8 b = *(const short8*)(wt_s + (ct * 16 + ln) * WT_STRIDE + k0 + qd * 8);
            acc[ct] = __builtin_amdgcn_mfma_f32_16x16x32_bf16(a, b, acc[ct], 0, 0, 0);
        }
    }

    __syncthreads();                    // wt_s dead; reuse as vals_s
    // C/D: col = ln, row = qd*4 + r (local row = wv*16 + qd*4 + r)
    #pragma unroll
    for (int ct = 0; ct < 7; ++ct) {
        int colg = ct * 16 + ln;
        if (colg < HC) {
            #pragma unroll
            for (int r = 0; r < 4; ++r)
                vals_s[((wv << 4) + (qd << 2) + r) * VS_STRIDE + colg] = acc[ct][r];
        }
    }
    __syncthreads();

    // pack: 64 nodes x 14 heads = 896 records
    for (int p = t; p < 64 * H; p += 256) {
        int nl = p / H, h = p - nl * H;
        int gn = rowBase + nl;
        if (gn >= N) break;
        const float* vp = vals_s + nl * VS_STRIDE + h * C;
        float v[C];
        float s1 = 0.f, s2 = 0.f;
        #pragma unroll
        for (int c2 = 0; c2 < C; ++c2) {
            float f = vp[c2];
            v[c2] = f;
            s1 = fmaf(f, as_s[h * C + c2], s1);
            s2 = fmaf(f, ad_s[h * C + c2], s2);
        }
        uint4 pk;
        pk.x = hpk(v[0], v[1]);
        pk.y = hpk(v[2], v[3]);
        pk.z = hpk(v[4], v[5]);
        pk.w = hpk(v[6], s1 * LOG2E);
        xpack[(size_t)gn * H + h] = pk;
        aldst[(size_t)gn * H + h] = s2 * LOG2E;
    }
}

// ---------------- layer-2 projection + pack (thread per node) ----------------

__global__ __launch_bounds__(256) void k_proj2_pack(
    const float* __restrict__ h1, const float* __restrict__ W,
    const float* __restrict__ asrc, const float* __restrict__ adst,
    uint4* __restrict__ xpack, float* __restrict__ aldst, int N)
{
    __shared__ float Ws[C * HC];
    __shared__ float as_s[HC], ad_s[HC];
    const int t = threadIdx.x;
    for (int i = t; i < C * HC; i += 256) Ws[i] = W[i];
    if (t < HC) { as_s[t] = asrc[t]; ad_s[t] = adst[t]; }
    __syncthreads();
    int n = blockIdx.x * 256 + t;
    if (n >= N) return;
    float xr[C];
    #pragma unroll
    for (int c2 = 0; c2 < C; ++c2) xr[c2] = h1[(size_t)n * C + c2];
    #pragma unroll
    for (int h = 0; h < H; ++h) {
        float v[C], s1 = 0.f, s2 = 0.f;
        #pragma unroll
        for (int c2 = 0; c2 < C; ++c2) {
            float acc = 0.f;
            #pragma unroll
            for (int k = 0; k < C; ++k)
                acc = fmaf(xr[k], Ws[k * HC + h * C + c2], acc);
            v[c2] = acc;
            s1 = fmaf(acc, as_s[h * C + c2], s1);
            s2 = fmaf(acc, ad_s[h * C + c2], s2);
        }
        uint4 pk;
        pk.x = hpk(v[0], v[1]);
        pk.y = hpk(v[2], v[3]);
        pk.z = hpk(v[4], v[5]);
        pk.w = hpk(v[6], s1 * LOG2E);
        xpack[(size_t)n * H + h] = pk;     // 224 B contiguous per thread
        aldst[(size_t)n * H + h] = s2 * LOG2E;
    }
}

// ---------------- fused aggregation: ONE WAVE PER NODE ----------------
// lane = e4*16 + h: e4 in 0..3 = edge slot, h in 0..15 = head (h<14 active).
// Fixed shift K = leaky(ld+2) makes softmax state LINEAR: partial den sums
// and partial channel-maxes combine across edge slots via shfl_xor(16,32);
// head-mean then reduces via shfl_xor(1,2,4,8). No LDS, no __syncthreads,
// serial gather chain per lane = deg/4 instead of deg.
#define AGG_STEP(DEN, REC)                                              \
    {                                                                   \
        float l = hhi((REC).w) + ld;                                    \
        float p = __builtin_amdgcn_exp2f(fmaxf(l, 0.2f * l) - K);       \
        DEN += p;                                                       \
        _Float16 ph = (_Float16)p;                                      \
        h2 p2 = { ph, ph };                                             \
        m0 = __builtin_elementwise_max(m0, p2 * u2h((REC).x));          \
        m1 = __builtin_elementwise_max(m1, p2 * u2h((REC).y));          \
        m2 = __builtin_elementwise_max(m2, p2 * u2h((REC).z));          \
        m3 = __builtin_elementwise_max(m3, p2 * u2h((REC).w));          \
    }

template<int LAYER>
__global__ __launch_bounds__(256) void k_agg(
    const int* __restrict__ row_ptr, const int* __restrict__ col,
    const uint4* __restrict__ xpack, const float* __restrict__ aldst,
    const float* __restrict__ bias,
    float* __restrict__ h1, float* __restrict__ out, int N)
{
    const int t    = threadIdx.x;
    const int lane = t & 63;
    const int e4   = lane >> 4;          // edge slot 0..3
    const int h    = lane & 15;          // head slot (active if < 14)
    const int n    = blockIdx.x * 4 + (t >> 6);
    const bool act = (h < H) && (n < N);

    float den = 0.f, den2 = 0.f;
    h2 m0 = u2h(0xFC00FC00u), m1 = m0, m2 = m0, m3 = m0;   // -inf packed
    float ld = 0.f, K = 0.f;

    if (act) {
        const int e0  = row_ptr[n];
        const int deg = row_ptr[n + 1] - e0;
        ld = aldst[(size_t)n * H + h];                     // already * log2e
        float kb = ld + 2.0f * LOG2E;
        K = fmaxf(kb, 0.2f * kb);                          // leaky(ld+2), log2 domain

        if (e4 == 0) {                                     // implicit self loop (once)
            uint4 pk = xpack[(size_t)n * H + h];
            float l = hhi(pk.w) + ld;
            float p = __builtin_amdgcn_exp2f(fmaxf(l, 0.2f * l) - K);
            den = p;
            _Float16 ph = (_Float16)p;
            h2 p2 = { ph, ph };
            m0 = p2 * u2h(pk.x);
            m1 = p2 * u2h(pk.y);
            m2 = p2 * u2h(pk.z);
            m3 = p2 * u2h(pk.w);                           // hi half ignored later
        }

        if (deg > 0) {
            const int last = deg - 1;
            int i = e4;                                    // edges i = e4 + 4k
            int c0 = col[e0 + min(i,      last)];
            int c1 = col[e0 + min(i + 4,  last)];
            uint4 r0 = xpack[(size_t)c0 * H + h];
            uint4 r1 = xpack[(size_t)c1 * H + h];
            c0 = col[e0 + min(i + 8,  last)];
            c1 = col[e0 + min(i + 12, last)];
            for (; i < deg; i += 8) {
                uint4 curA = r0, curB = r1;
                r0 = xpack[(size_t)c0 * H + h];
                r1 = xpack[(size_t)c1 * H + h];
                c0 = col[e0 + min(i + 16, last)];
                c1 = col[e0 + min(i + 20, last)];
                AGG_STEP(den,  curA);                      // edge i
                if (i + 4 < deg) AGG_STEP(den2, curB);     // edge i+4
            }
        }
    }
    den += den2;

    // ---- combine across edge slots (lanes h, h+16, h+32, h+48) ----
    den += __shfl_xor(den, 16, 64);
    den += __shfl_xor(den, 32, 64);
    m0 = hshfl_max(m0, 16); m0 = hshfl_max(m0, 32);
    m1 = hshfl_max(m1, 16); m1 = hshfl_max(m1, 32);
    m2 = hshfl_max(m2, 16); m2 = hshfl_max(m2, 32);
    m3 = hshfl_max(m3, 16); m3 = hshfl_max(m3, 32);

    float v[C];
    if (act) {
        float rd = 1.f / den;                              // den >= p_self > 0
        v[0] = (float)m0.x * rd; v[1] = (float)m0.y * rd;
        v[2] = (float)m1.x * rd; v[3] = (float)m1.y * rd;
        v[4] = (float)m2.x * rd; v[5] = (float)m2.y * rd;
        v[6] = (float)m3.x * rd;
    } else {
        #pragma unroll
        for (int c = 0; c < C; ++c) v[c] = 0.f;
    }

    // ---- head mean across 16-lane group ----
    #pragma unroll
    for (int off = 1; off <= 8; off <<= 1) {
        #pragma unroll
        for (int c = 0; c < C; ++c) v[c] += __shfl_xor(v[c], off, 64);
    }

    if (n >= N) return;
    if (LAYER == 1) {
        if (lane < C) {
            float myv = v[0];
            #pragma unroll
            for (int c = 1; c < C; ++c) if (lane == c) myv = v[c];
            h1[(size_t)n * C + lane] = fmaxf(myv * (1.f / H) + bias[lane], 0.f);
        }
    } else {
        float o[C];
        #pragma unroll
        for (int c = 0; c < C; ++c) o[c] = v[c] * (1.f / H) + bias[c];
        float mv = o[0];
        #pragma unroll
        for (int c = 1; c < C; ++c) mv = fmaxf(mv, o[c]);
        float lse = 0.f;
        #pragma unroll
        for (int c = 0; c < C; ++c) lse += __expf(o[c] - mv);
        lse = logf(lse);
        if (lane < C) {
            float myo = o[0];
            #pragma unroll
            for (int c = 1; c < C; ++c) if (lane == c) myo = o[c];
            out[(size_t)n * C + lane] = myo - mv - lse;
        }
    }
}

// ---------------- launch ----------------

static inline size_t align16(size_t v) { return (v + 15) & ~(size_t)15; }

extern "C" void kernel_launch(void* const* d_in, const int* in_sizes, int n_in,
                              void* d_out, int out_size, void* d_ws, size_t ws_size,
                              hipStream_t stream)
{
    const float* x     = (const float*)d_in[0];
    const int*   ei    = (const int*)d_in[1];
    const float* W1    = (const float*)d_in[2];
    const float* asrc1 = (const float*)d_in[3];
    const float* adst1 = (const float*)d_in[4];
    const float* b1    = (const float*)d_in[5];
    const float* W2    = (const float*)d_in[6];
    const float* asrc2 = (const float*)d_in[7];
    const float* adst2 = (const float*)d_in[8];
    const float* b2    = (const float*)d_in[9];

    const int N  = in_sizes[0] / FIN;   // 100000
    const int E  = in_sizes[1] / 2;     // 1600000
    const int nb = (N + BSIZE - 1) >> BSHIFT;   // 196

    char* w = (char*)d_ws;
    uint4* xpack   = (uint4*)w; w += align16((size_t)N * H * 16);   // 22.4 MB
    int2*  pedge   = (int2*)w;  w += align16((size_t)E * 8);        // 12.8 MB
    float* aldst   = (float*)w; w += align16((size_t)N * H * 4);    //  5.6 MB
    float* h1      = (float*)w; w += align16((size_t)N * C * 4);    //  2.8 MB
    int*   row_ptr = (int*)w;   w += align16((size_t)(N + 1) * 4);
    int*   col     = (int*)w;   w += align16((size_t)E * 4);        //  6.4 MB
    int*   gcnt    = (int*)w;   w += align16((size_t)nb * 4);
    int*   boff    = (int*)w;   w += align16((size_t)(nb + 1) * 4);
    int*   bcur    = (int*)w;   w += align16((size_t)nb * 4);
    unsigned short* WtG = (unsigned short*)w; w += align16((size_t)WT_ROWS * FIN * 2);

    const int gAgg  = (N + 3) / 4;      // one wave per node, 4 waves/block
    const int gMfma = (N + 63) / 64;
    const int g256N = (N + 255) / 256;

    // ---- bucketed CSR build (no self loops; rebuilt every call) ----
    k_zero<<<1, 256, 0, stream>>>(gcnt, nb);
    k_hist<<<256, 256, 0, stream>>>(ei, E, gcnt, nb);
    k_bscan<<<1, 1024, 0, stream>>>(gcnt, boff, bcur, row_ptr, nb, N);
    k_part<<<256, 256, 0, stream>>>(ei, E, bcur, pedge, nb);
    k_bcsr<<<nb, 512, 0, stream>>>(pedge, boff, row_ptr, col, N);

    // ---- layer 1 ----
    k_convW<<<(WT_ROWS * FIN + 255) / 256, 256, 0, stream>>>(W1, WtG);
    k_proj1_mfma<<<gMfma, 256, 0, stream>>>(x, WtG, asrc1, adst1, xpack, aldst, N);
    k_agg<1><<<gAgg, 256, 0, stream>>>(row_ptr, col, xpack, aldst, b1,
                                       h1, (float*)d_out, N);
    // ---- layer 2 ----
    k_proj2_pack<<<g256N, 256, 0, stream>>>(h1, W2, asrc2, adst2, xpack, aldst, N);
    k_agg<2><<<gAgg, 256, 0, stream>>>(row_ptr, col, xpack, aldst, b2,
                                       h1, (float*)d_out, N);
}